// Round 4
// baseline (337.479 us; speedup 1.0000x reference)
//
#include <hip/hip_runtime.h>

namespace {
constexpr int kInCh  = 64;
constexpr int kOutCh = 64;
constexpr int kK     = 3;
constexpr int kFanIn = 8;
constexpr int kH     = 1024;
constexpr int kTile  = 128;          // h-positions per block
constexpr int kRow   = kTile + 8;    // LDS row: 4-float halo each side, float4-aligned stores
}

struct Tap { int off; float w; };

// input fake-quant: clip(round(v*16), -128, 127) * 0.0625
// *16 exact (pow2); rintf = round-half-even = np.round. STE forward == q exactly
// (q - v exact by Sterbenz for |q-v| <= scale/2, no clipping for N(0,1) inputs).
__device__ __forceinline__ float quant_in(float v) {
    float q = rintf(v * 16.0f);
    q = fmaxf(q, -128.0f);
    q = fminf(q, 127.0f);
    return q * 0.0625f;
}

// output fake-quant in fp32 (ref conv+quant is fp32; *8 and *0.125 exact pow2)
__device__ __forceinline__ float quant_out(float v) {
    float q = rintf(v * 8.0f);
    q = fmaxf(q, -128.0f);
    q = fminf(q, 127.0f);
    return q * 0.125f;
}

// Taps in XLA-CPU/Eigen contraction order: flattened (kw, ci) with ci INNERMOST
// (NHWC patches x HWIO kernel). Exactly kFanIn nonzero taps per o; zero terms of
// the dense chain are exact no-ops under fma, so the compacted chain is bit-equal.
__global__ void prep_taps(const float* __restrict__ weight,
                          const float* __restrict__ mask,
                          Tap* __restrict__ taps) {
    int o = threadIdx.x;
    if (o >= kOutCh) return;
    const float* mrow = mask   + o * kInCh * kK;
    const float* wrow = weight + o * kInCh * kK;
    int cnt = 0;
    for (int k = 0; k < kK; ++k) {            // k outer
        for (int ci = 0; ci < kInCh; ++ci) {  // ci inner (fastest)
            int j = ci * kK + k;              // OIH storage index
            float m = mrow[j];
            if (m != 0.0f && cnt < kFanIn) {
                taps[o * kFanIn + cnt].off = ci * kRow + k + 3;
                taps[o * kFanIn + cnt].w   = wrow[j] * m;
                ++cnt;
            }
        }
    }
    for (; cnt < kFanIn; ++cnt) {   // safety pad (ws is poisoned 0xAA)
        taps[o * kFanIn + cnt].off = 3;
        taps[o * kFanIn + cnt].w   = 0.0f;
    }
}

__global__ __launch_bounds__(256, 4) void sparse_conv(
        const float* __restrict__ x,
        const Tap*   __restrict__ taps,
        float*       __restrict__ out) {
    __shared__ float sm[kInCh * kRow];   // 34.8 KiB -> 4 blocks/CU

    const int t  = threadIdx.x;
    const int h0 = blockIdx.x * kTile;
    const int n  = blockIdx.y;
    const float* __restrict__ xn = x + (size_t)n * kInCh * kH;

    // ---- stage x tile into LDS, quantized once on load ----
    #pragma unroll
    for (int it = 0; it < 8; ++it) {
        int f  = it * 256 + t;
        int ci = f >> 5;          // 32 float4 per row
        int c4 = f & 31;
        float4 v = reinterpret_cast<const float4*>(xn + ci * kH + h0)[c4];
        v.x = quant_in(v.x); v.y = quant_in(v.y);
        v.z = quant_in(v.z); v.w = quant_in(v.w);
        reinterpret_cast<float4*>(&sm[ci * kRow + 4])[c4] = v;
    }
    if (t < 64) {                 // left halo (only h0-1 is ever read)
        int ci = t;
        float4 v = make_float4(0.f, 0.f, 0.f, 0.f);
        if (h0 > 0) v = *reinterpret_cast<const float4*>(xn + ci * kH + h0 - 4);
        v.x = quant_in(v.x); v.y = quant_in(v.y);
        v.z = quant_in(v.z); v.w = quant_in(v.w);
        *reinterpret_cast<float4*>(&sm[ci * kRow]) = v;
    } else if (t < 128) {         // right halo (only h0+kTile is ever read)
        int ci = t - 64;
        float4 v = make_float4(0.f, 0.f, 0.f, 0.f);
        if (h0 + kTile < kH) v = *reinterpret_cast<const float4*>(xn + ci * kH + h0 + kTile);
        v.x = quant_in(v.x); v.y = quant_in(v.y);
        v.z = quant_in(v.z); v.w = quant_in(v.w);
        *reinterpret_cast<float4*>(&sm[ci * kRow + 4 + kTile]) = v;
    }
    __syncthreads();

    // ---- compute: wave owns 16 output channels; thread does h-pair {i, i+64} ----
    const int g = __builtin_amdgcn_readfirstlane(t >> 6);   // wave-uniform o-group
    const int i = t & 63;
    float* __restrict__ outn = out + (size_t)n * kOutCh * kH + h0;

    #pragma unroll 2
    for (int oo = 0; oo < 16; ++oo) {
        int o = g * 16 + oo;
        const Tap* __restrict__ tp = taps + o * kFanIn;

        // Single sequential fp32 FMA chain in (k-major, ci-minor) tap order —
        // replicates Eigen gebp's one-accumulator k-loop on the im2col matrix.
        float acc0 = 0.f, acc1 = 0.f;
        #pragma unroll
        for (int j = 0; j < kFanIn; ++j) {
            int off = tp[j].off; float w = tp[j].w;
            acc0 = fmaf(w, sm[off + i],      acc0);
            acc1 = fmaf(w, sm[off + i + 64], acc1);
        }
        outn[o * kH + i]      = quant_out(acc0);
        outn[o * kH + i + 64] = quant_out(acc1);
    }
}

extern "C" void kernel_launch(void* const* d_in, const int* in_sizes, int n_in,
                              void* d_out, int out_size, void* d_ws, size_t ws_size,
                              hipStream_t stream) {
    const float* x      = (const float*)d_in[0];
    const float* weight = (const float*)d_in[1];
    const float* mask   = (const float*)d_in[2];
    float* out = (float*)d_out;
    Tap* taps = (Tap*)d_ws;   // 64*8*8 B = 4 KiB of workspace

    const int nBatch = in_sizes[0] / (kInCh * kH);   // 512

    prep_taps<<<1, 64, 0, stream>>>(weight, mask, taps);
    dim3 grid(kH / kTile, nBatch);
    sparse_conv<<<grid, 256, 0, stream>>>(x, taps, out);
}

// Round 5
// 242.008 us; speedup vs baseline: 1.3945x; 1.3945x over previous
//
#include <hip/hip_runtime.h>

namespace {
constexpr int kInCh  = 64;
constexpr int kOutCh = 64;
constexpr int kK     = 3;
constexpr int kFanIn = 8;
constexpr int kH     = 1024;
constexpr int kTile  = 128;          // h-positions per block
constexpr int kRow   = kTile + 8;    // LDS row: 4-float halo each side, float4-aligned stores
}

struct Tap { int off; float w; };

// input fake-quant: clip(round(v*16), -128, 127) * 0.0625
// *16 exact (pow2); rintf = round-half-even = np.round. STE forward == q exactly.
__device__ __forceinline__ float quant_in(float v) {
    float q = rintf(v * 16.0f);
    q = fmaxf(q, -128.0f);
    q = fminf(q, 127.0f);
    return q * 0.0625f;
}

// output fake-quant in fp32 (ref conv+quant is fp32; *8 and *0.125 exact pow2)
__device__ __forceinline__ float quant_out(float v) {
    float q = rintf(v * 8.0f);
    q = fmaxf(q, -128.0f);
    q = fminf(q, 127.0f);
    return q * 0.125f;
}

// VERIFIED (round 4, absmax=0.0): reference == single fp32 FMA chain per output in
// (k-major, ci-minor) tap order — Eigen im2col contraction order. DO NOT change
// tap ordering or accumulation structure.
//
// Parallel stable compaction: 64 blocks (one per o) x 192 threads (one per key
// j = k*64 + ci). Rank = count of nonzero keys < j, via per-wave ballots.
// Round-4's single-wave scan serialized ~384 dependent-guarded global loads
// -> 101 us; this version is ~2 loads/thread, fully parallel.
__global__ void prep_taps(const float* __restrict__ weight,
                          const float* __restrict__ mask,
                          Tap* __restrict__ taps) {
    __shared__ unsigned long long bal[3];
    const int o    = blockIdx.x;
    const int j    = threadIdx.x;        // key: k*64 + ci  (wave index == k)
    const int k    = j >> 6;
    const int ci   = j & 63;
    const int idx  = (o * kInCh + ci) * kK + k;   // OIH storage

    const float m = mask[idx];
    const unsigned long long b = __ballot(m != 0.0f);
    if (ci == 0) bal[k] = b;
    __syncthreads();

    const unsigned long long lower = b & ((1ull << ci) - 1ull);
    int rank = __popcll(lower);
    #pragma unroll
    for (int w = 0; w < kK; ++w) if (w < k) rank += __popcll(bal[w]);

    if (m != 0.0f && rank < kFanIn) {
        taps[o * kFanIn + rank].off = ci * kRow + k + 3;
        taps[o * kFanIn + rank].w   = weight[idx] * m;
    }
    // zero-pad slots beyond the total nonzero count (ws is poisoned 0xAA)
    int total = __popcll(bal[0]) + __popcll(bal[1]) + __popcll(bal[2]);
    if (j >= total && j < kFanIn) {
        taps[o * kFanIn + j].off = 3;
        taps[o * kFanIn + j].w   = 0.0f;
    }
}

__global__ __launch_bounds__(256, 4) void sparse_conv(
        const float* __restrict__ x,
        const Tap*   __restrict__ taps,
        float*       __restrict__ out) {
    __shared__ float sm[kInCh * kRow];   // 34.8 KiB -> 4 blocks/CU

    const int t  = threadIdx.x;
    const int h0 = blockIdx.x * kTile;
    const int n  = blockIdx.y;
    const float* __restrict__ xn = x + (size_t)n * kInCh * kH;

    // ---- stage x tile into LDS, quantized once on load ----
    #pragma unroll
    for (int it = 0; it < 8; ++it) {
        int f  = it * 256 + t;
        int ci = f >> 5;          // 32 float4 per row
        int c4 = f & 31;
        float4 v = reinterpret_cast<const float4*>(xn + ci * kH + h0)[c4];
        v.x = quant_in(v.x); v.y = quant_in(v.y);
        v.z = quant_in(v.z); v.w = quant_in(v.w);
        reinterpret_cast<float4*>(&sm[ci * kRow + 4])[c4] = v;
    }
    if (t < 64) {                 // left halo (only h0-1 is ever read)
        int ci = t;
        float4 v = make_float4(0.f, 0.f, 0.f, 0.f);
        if (h0 > 0) v = *reinterpret_cast<const float4*>(xn + ci * kH + h0 - 4);
        v.x = quant_in(v.x); v.y = quant_in(v.y);
        v.z = quant_in(v.z); v.w = quant_in(v.w);
        *reinterpret_cast<float4*>(&sm[ci * kRow]) = v;
    } else if (t < 128) {         // right halo (only h0+kTile is ever read)
        int ci = t - 64;
        float4 v = make_float4(0.f, 0.f, 0.f, 0.f);
        if (h0 + kTile < kH) v = *reinterpret_cast<const float4*>(xn + ci * kH + h0 + kTile);
        v.x = quant_in(v.x); v.y = quant_in(v.y);
        v.z = quant_in(v.z); v.w = quant_in(v.w);
        *reinterpret_cast<float4*>(&sm[ci * kRow + 4 + kTile]) = v;
    }
    __syncthreads();

    // ---- compute: wave owns 16 output channels; thread does h-pair {i, i+64} ----
    const int g = __builtin_amdgcn_readfirstlane(t >> 6);   // wave-uniform o-group
    const int i = t & 63;
    float* __restrict__ outn = out + (size_t)n * kOutCh * kH + h0;

    #pragma unroll 2
    for (int oo = 0; oo < 16; ++oo) {
        int o = g * 16 + oo;
        const Tap* __restrict__ tp = taps + o * kFanIn;

        // Single sequential fp32 FMA chain in (k-major, ci-minor) tap order —
        // bit-matches the reference (verified round 4, absmax = 0.0).
        float acc0 = 0.f, acc1 = 0.f;
        #pragma unroll
        for (int j = 0; j < kFanIn; ++j) {
            int off = tp[j].off; float w = tp[j].w;
            acc0 = fmaf(w, sm[off + i],      acc0);
            acc1 = fmaf(w, sm[off + i + 64], acc1);
        }
        outn[o * kH + i]      = quant_out(acc0);
        outn[o * kH + i + 64] = quant_out(acc1);
    }
}

extern "C" void kernel_launch(void* const* d_in, const int* in_sizes, int n_in,
                              void* d_out, int out_size, void* d_ws, size_t ws_size,
                              hipStream_t stream) {
    const float* x      = (const float*)d_in[0];
    const float* weight = (const float*)d_in[1];
    const float* mask   = (const float*)d_in[2];
    float* out = (float*)d_out;
    Tap* taps = (Tap*)d_ws;   // 64*8*8 B = 4 KiB of workspace

    const int nBatch = in_sizes[0] / (kInCh * kH);   // 512

    prep_taps<<<kOutCh, kInCh * kK, 0, stream>>>(weight, mask, taps);
    dim3 grid(kH / kTile, nBatch);
    sparse_conv<<<grid, 256, 0, stream>>>(x, taps, out);
}

// Round 6
// 237.556 us; speedup vs baseline: 1.4206x; 1.0187x over previous
//
#include <hip/hip_runtime.h>

namespace {
constexpr int kInCh  = 64;
constexpr int kOutCh = 64;
constexpr int kK     = 3;
constexpr int kFanIn = 8;
constexpr int kH     = 1024;
constexpr int kTile  = 128;          // h-positions per block
constexpr int kRow   = kTile + 8;    // LDS row: 4-float halo each side, float4-aligned stores
constexpr int kBlk   = 512;          // 8 waves: 4 blocks/CU x 8 waves = 32 waves/CU (full occupancy)
}

struct Tap { int off; float w; };

// input fake-quant: clip(round(v*16), -128, 127) * 0.0625
// *16 exact (pow2); rintf = round-half-even = np.round. STE forward == q exactly.
__device__ __forceinline__ float quant_in(float v) {
    float q = rintf(v * 16.0f);
    q = fmaxf(q, -128.0f);
    q = fminf(q, 127.0f);
    return q * 0.0625f;
}

// output fake-quant in fp32 (ref conv+quant is fp32; *8 and *0.125 exact pow2)
__device__ __forceinline__ float quant_out(float v) {
    float q = rintf(v * 8.0f);
    q = fmaxf(q, -128.0f);
    q = fminf(q, 127.0f);
    return q * 0.125f;
}

// VERIFIED (round 4, absmax=0.0): reference == single fp32 FMA chain per output in
// (k-major, ci-minor) tap order — Eigen im2col contraction order. DO NOT change
// tap ordering or accumulation structure.
//
// Parallel stable compaction: 64 blocks (one per o) x 192 threads (one per key
// j = k*64 + ci). Rank = count of nonzero keys < j, via per-wave ballots.
__global__ void prep_taps(const float* __restrict__ weight,
                          const float* __restrict__ mask,
                          Tap* __restrict__ taps) {
    __shared__ unsigned long long bal[3];
    const int o    = blockIdx.x;
    const int j    = threadIdx.x;        // key: k*64 + ci  (wave index == k)
    const int k    = j >> 6;
    const int ci   = j & 63;
    const int idx  = (o * kInCh + ci) * kK + k;   // OIH storage

    const float m = mask[idx];
    const unsigned long long b = __ballot(m != 0.0f);
    if (ci == 0) bal[k] = b;
    __syncthreads();

    const unsigned long long lower = b & ((1ull << ci) - 1ull);
    int rank = __popcll(lower);
    #pragma unroll
    for (int w = 0; w < kK; ++w) if (w < k) rank += __popcll(bal[w]);

    if (m != 0.0f && rank < kFanIn) {
        taps[o * kFanIn + rank].off = ci * kRow + k + 3;
        taps[o * kFanIn + rank].w   = weight[idx] * m;
    }
    // zero-pad slots beyond the total nonzero count (ws is poisoned 0xAA)
    int total = __popcll(bal[0]) + __popcll(bal[1]) + __popcll(bal[2]);
    if (j >= total && j < kFanIn) {
        taps[o * kFanIn + j].off = 3;
        taps[o * kFanIn + j].w   = 0.0f;
    }
}

// block=512 (8 waves): LDS 34.8 KiB -> 4 blocks/CU, 32 waves/CU = 100% occupancy.
// Round 5 at block=256 measured Occupancy 32%, VALUBusy 23%, HBM 35% -> latency-bound;
// doubling resident waves is the one-knob fix (VGPR 52 <= 64 cap at 8 waves/SIMD).
__global__ __launch_bounds__(kBlk, 8) void sparse_conv(
        const float* __restrict__ x,
        const Tap*   __restrict__ taps,
        float*       __restrict__ out) {
    __shared__ float sm[kInCh * kRow];

    const int t  = threadIdx.x;
    const int h0 = blockIdx.x * kTile;
    const int n  = blockIdx.y;
    const float* __restrict__ xn = x + (size_t)n * kInCh * kH;

    // ---- stage x tile into LDS, quantized once on load ----
    // 64 rows x 32 float4 = 2048 float4, 512 threads -> 4 iters, coalesced
    #pragma unroll
    for (int it = 0; it < 4; ++it) {
        int f  = it * kBlk + t;
        int ci = f >> 5;          // 32 float4 per row
        int c4 = f & 31;
        float4 v = reinterpret_cast<const float4*>(xn + ci * kH + h0)[c4];
        v.x = quant_in(v.x); v.y = quant_in(v.y);
        v.z = quant_in(v.z); v.w = quant_in(v.w);
        reinterpret_cast<float4*>(&sm[ci * kRow + 4])[c4] = v;
    }
    if (t < 64) {                 // left halo (only h0-1 is ever read)
        int ci = t;
        float4 v = make_float4(0.f, 0.f, 0.f, 0.f);
        if (h0 > 0) v = *reinterpret_cast<const float4*>(xn + ci * kH + h0 - 4);
        v.x = quant_in(v.x); v.y = quant_in(v.y);
        v.z = quant_in(v.z); v.w = quant_in(v.w);
        *reinterpret_cast<float4*>(&sm[ci * kRow]) = v;
    } else if (t < 128) {         // right halo (only h0+kTile is ever read)
        int ci = t - 64;
        float4 v = make_float4(0.f, 0.f, 0.f, 0.f);
        if (h0 + kTile < kH) v = *reinterpret_cast<const float4*>(xn + ci * kH + h0 + kTile);
        v.x = quant_in(v.x); v.y = quant_in(v.y);
        v.z = quant_in(v.z); v.w = quant_in(v.w);
        *reinterpret_cast<float4*>(&sm[ci * kRow + 4 + kTile]) = v;
    }
    __syncthreads();

    // ---- compute: each of 8 waves owns 8 output channels; thread does h-pair {i, i+64} ----
    const int g = __builtin_amdgcn_readfirstlane(t >> 6);   // wave-uniform o-group (0..7)
    const int i = t & 63;
    float* __restrict__ outn = out + (size_t)n * kOutCh * kH + h0;

    #pragma unroll 2
    for (int oo = 0; oo < 8; ++oo) {
        int o = g * 8 + oo;
        const Tap* __restrict__ tp = taps + o * kFanIn;

        // Single sequential fp32 FMA chain in (k-major, ci-minor) tap order —
        // bit-matches the reference (verified round 4, absmax = 0.0).
        // Pair {i, i+64} -> ds_read2_b32 (offsets 64 dwords apart), stride-1 lanes.
        float acc0 = 0.f, acc1 = 0.f;
        #pragma unroll
        for (int j = 0; j < kFanIn; ++j) {
            int off = tp[j].off; float w = tp[j].w;
            acc0 = fmaf(w, sm[off + i],      acc0);
            acc1 = fmaf(w, sm[off + i + 64], acc1);
        }
        outn[o * kH + i]      = quant_out(acc0);
        outn[o * kH + i + 64] = quant_out(acc1);
    }
}

extern "C" void kernel_launch(void* const* d_in, const int* in_sizes, int n_in,
                              void* d_out, int out_size, void* d_ws, size_t ws_size,
                              hipStream_t stream) {
    const float* x      = (const float*)d_in[0];
    const float* weight = (const float*)d_in[1];
    const float* mask   = (const float*)d_in[2];
    float* out = (float*)d_out;
    Tap* taps = (Tap*)d_ws;   // 64*8*8 B = 4 KiB of workspace

    const int nBatch = in_sizes[0] / (kInCh * kH);   // 512

    prep_taps<<<kOutCh, kInCh * kK, 0, stream>>>(weight, mask, taps);
    dim3 grid(kH / kTile, nBatch);
    sparse_conv<<<grid, kBlk, 0, stream>>>(x, taps, out);
}